// Round 13
// baseline (333.211 us; speedup 1.0000x reference)
//
#include <hip/hip_runtime.h>

// ScaledDotProductAttention: B=4, NQ=NK=2048, D_MODEL=D_K=D_V=1024, H=16, HD=64.
// R18: proj traffic cut via tile reshape. Evidence: SEVEN sync/pipeline
// variants pinned proj at two plateaus (148-166us scattered-address,
// 108-109us coalesced) -- time tracks STAGED BYTES, not schedule. At
// BM128/BN256 A is staged 4x (768MB total). Now BM=64/BN=512: A staged 2x ->
// 576MB (-25%); buffers 36KB (A 4KB + B 32KB) x2 = 72KB; grid 128x2x3 = 768
// = 3/CU balanced. R14's proven 2-phase sync + asm ds_reads retained.
//  1) make_wgroups : W* -> group layout; Wq/Wk/Wv re-grouped for BN512/BK32
//                    panels (p = ct2*32+ks, 32 x 1KB groups); Wo unchanged.
//  2) proj_kernel  : 64x512, BK=32, 512thr (8 waves 1x8, wave=64x64).
//                    A staged by waves 0-3 (2 float4 -> cvt_pk -> swizzled
//                    ds_write_b128); B 4 contiguous 1KB gload_lds per wave.
//  3) attn_kernel  : unchanged (KVg contiguous staging, 128-key tiles).
//  4) out_kernel   : unchanged (R17 counted template).
// Workspace 72 MiB: Wg 4x2MB | Qh 16MB | KVg 32MB | Obf 16MB.

#define DM    1024
#define NSEQ  2048
#define HEADS 16
#define HD    64

typedef float floatx4 __attribute__((ext_vector_type(4)));
typedef short s16x4   __attribute__((ext_vector_type(4)));
typedef short s16x8   __attribute__((ext_vector_type(8)));
typedef unsigned int u32x4 __attribute__((ext_vector_type(4)));

static __device__ __forceinline__ floatx4 mfma_bf16(s16x8 a, s16x8 b, floatx4 c) {
  return __builtin_amdgcn_mfma_f32_16x16x32_bf16(a, b, c, 0, 0, 0);
}

// Async global->LDS DMA, 16B per lane: dest = wave-uniform base + lane*16,
// source = per-lane global address (contiguous 1KB per instruction here).
static __device__ __forceinline__ void gload_lds16(const void* g, void* l) {
  __builtin_amdgcn_global_load_lds(
      (const __attribute__((address_space(1))) unsigned*)g,
      (__attribute__((address_space(3))) unsigned*)l, 16, 0, 0);
}

static __device__ __forceinline__ unsigned lds_addr(const void* p) {
  return (unsigned)(unsigned long long)p;
}

// Inline-asm ds_read_b128 (opaque to alias analysis -> no compiler-inserted
// vmcnt(0) drain; caller fences with lgkmcnt(0)+sched_barrier per rule #18).
static __device__ __forceinline__ s16x8 ds_read_b128a(unsigned byteaddr) {
  s16x8 r;
  asm volatile("ds_read_b128 %0, %1" : "=v"(r) : "v"(byteaddr));
  return r;
}

#define SCHED0() __builtin_amdgcn_sched_barrier(0)
#define WAIT_LGKM0() \
  { asm volatile("s_waitcnt lgkmcnt(0)" ::: "memory"); __builtin_amdgcn_sched_barrier(0); }
#define WAIT_VMCNT(N) \
  { asm volatile("s_waitcnt vmcnt(" #N ")" ::: "memory"); __builtin_amdgcn_sched_barrier(0); }

// fp32 -> bf16 round-to-nearest-even (bit trick; inputs are finite)
static __device__ __forceinline__ short f2bf(float f) {
  unsigned u = __builtin_bit_cast(unsigned, f);
  u += 0x7FFFu + ((u >> 16) & 1u);
  return (short)(u >> 16);
}

// Packed fp32 pair -> 2 bf16 (RNE, same result as f2bf) in one VALU op.
static __device__ __forceinline__ unsigned cvtpk_bf16(float lo, float hi) {
  unsigned r;
  asm("v_cvt_pk_bf16_f32 %0, %1, %2" : "=v"(r) : "v"(lo), "v"(hi));
  return r;
}

// Pack 2 fp32 -> 2 bf16 in one u32 (round-half-up; attn P-values only).
static __device__ __forceinline__ unsigned pack2_bf16(float a, float b) {
  unsigned ua = __builtin_bit_cast(unsigned, a) + 0x8000u;
  unsigned ub = __builtin_bit_cast(unsigned, b) + 0x8000u;
#if __has_builtin(__builtin_amdgcn_perm)
  return __builtin_amdgcn_perm(ub, ua, 0x07060302u);
#else
  return (ub & 0xffff0000u) | (ua >> 16);
#endif
}

// ---------------------------------------------------------------------------
// 1) Weights -> fragment-group layouts.
//    Wq/Wk/Wv (BN512/BK32 panels): panel p = ct2*32 + ks (ct2 in 0..1, ks in
//    0..31) = 32 groups x 1KB at p*16384 shorts; group gb = col16 (0..31
//    within the 512-col tile); chunk l': W^T[ct2*512 + gb*16 + lm][ks*32 +
//    quad*8 + e].
//    Wo (BN128/BK64 panels, unchanged): panel (ct*16+ks)*8192, 16 groups.
__global__ __launch_bounds__(256) void make_wgroups(
    const float* __restrict__ W0, const float* __restrict__ W1,
    const float* __restrict__ W2, const float* __restrict__ W3,
    short* __restrict__ G0, short* __restrict__ G1,
    short* __restrict__ G2, short* __restrict__ G3) {
  __shared__ float tile[64][68];  // [k][n], padded
  const int m = blockIdx.z;
  const float* W = m == 0 ? W0 : m == 1 ? W1 : m == 2 ? W2 : W3;
  short*       G = m == 0 ? G0 : m == 1 ? G1 : m == 2 ? G2 : G3;
  const int nt = blockIdx.x, kt = blockIdx.y;  // 16 x 16 tiles of 64x64
  const int n0 = nt * 64, k0 = kt * 64;
  const int t = threadIdx.x;
  for (int j = 0; j < 4; j++) {
    int idx = j * 256 + t, r = idx >> 4, cq = idx & 15;
    *(floatx4*)&tile[r][cq * 4] = *(const floatx4*)(W + (long)(k0 + r) * DM + n0 + cq * 4);
  }
  __syncthreads();
  for (int j = 0; j < 2; j++) {
    int ci = j * 256 + t;
    int lm = ci & 15, quad = (ci >> 4) & 3, kk = (ci >> 6) & 1, gl = ci >> 7;
    s16x8 v;
#pragma unroll
    for (int e = 0; e < 8; e++) v[e] = f2bf(tile[kk * 32 + quad * 8 + e][gl * 16 + lm]);
    long addr;
    if (m < 3) {
      // BN512/BK32: panel p = ct2*32 + (kt*2+kk); group gb = (nt&7)*4 + gl.
      int ct2 = nt >> 3;
      int p = ct2 * 32 + kt * 2 + kk;
      int gb = (nt & 7) * 4 + gl;
      addr = (long)p * 16384 + gb * 512 + (quad * 16 + lm) * 8;
    } else {
      int ct = nt >> 1, g16 = (nt & 1) * 4 + gl;
      addr = ((long)(ct * 16 + kt)) * 8192 + (g16 * 2 + kk) * 512 + (quad * 16 + lm) * 8;
    }
    *(s16x8*)(G + addr) = v;
  }
}

// ---------------------------------------------------------------------------
// 2) Projection GEMM: C[8192x1024] = A(fp32) @ W.  64x512 tile, BK=32, 512thr.
//    Per 36KiB buffer: A bf16 4 groups x 1KiB at byte g16*1024, swizzled slot
//    q*16 + (lm2 ^ (q*2)); B bf16 32 groups at byte 4096 + gb*1024, linear
//    (one BN512/BK32 Wg panel per step).
//    8 waves 1x8: wave w owns cols col0 + w*64 (single head). acc[4][4].
//    A staged by waves 0..3: thread t<256: row t>>2, 8 floats at (t&3)*8 ->
//    2 cvt_pk pairs -> one swizzled ds_write_b128. B: 4 contiguous 1KB
//    gload_lds per wave. R14 2-phase sync (proven): issue next, process cur,
//    write next, __syncthreads.
//    z=0:->Qh (PRE-SCALED log2e/sqrt(1024)), z=1: K->KVg 0..15, z=2: V->KVg
//    16..31 (interleaved keys).
__global__ __launch_bounds__(512, 2) void proj_kernel(
    const float* __restrict__ Aq, const float* __restrict__ Ak, const float* __restrict__ Av,
    const short* __restrict__ BgQ, const short* __restrict__ BgK, const short* __restrict__ BgV,
    short* __restrict__ Qh, short* __restrict__ KVg) {
  __shared__ short lds[2 * 18432];  // 2 x 36 KiB (A 4KB + B 32KB)
  const int z = blockIdx.z;
  const float* A  = z == 0 ? Aq  : z == 1 ? Ak  : Av;
  const short* Bg = z == 0 ? BgQ : z == 1 ? BgK : BgV;
  const int t = threadIdx.x;
  const int w = t >> 6, l = t & 63, quad = l >> 4, lm = l & 15;
  const int row0 = blockIdx.x * 64;
  const int ct2 = blockIdx.y;         // 512-col tile (0..1)
  const int col0 = ct2 * 512;

  floatx4 acc[4][4];
  for (int mi = 0; mi < 4; mi++)
    for (int ni = 0; ni < 4; ni++) acc[mi][ni] = (floatx4){0.f, 0.f, 0.f, 0.f};

  // A stage (waves 0..3 only; wave-uniform predicate): thread t<256 covers
  // row t>>2 (0..63), 8 floats at k = ks*32 + (t&3)*8 (128B-coalesced rows).
  floatx4 a0, a1;
  auto loadA = [&](int ks) __attribute__((always_inline)) {
    if (t < 256) {
      const float* p = A + (long)(row0 + (t >> 2)) * DM + ks * 32 + (t & 3) * 8;
      a0 = *(const floatx4*)p;
      a1 = *(const floatx4*)(p + 4);
    }
  };
  auto writeA = [&](int buf) __attribute__((always_inline)) {
    if (t < 256) {
      int row = t >> 2, q = t & 3, lm2 = row & 15, g16 = row >> 4;
      u32x4 pk = {cvtpk_bf16(a0[0], a0[1]), cvtpk_bf16(a0[2], a0[3]),
                  cvtpk_bf16(a1[0], a1[1]), cvtpk_bf16(a1[2], a1[3])};
      int s = q * 16 + (lm2 ^ (q * 2));  // XOR swizzle (2-way max, R14-proven)
      *(s16x8*)(lds + buf * 18432 + g16 * 512 + s * 8) =
          __builtin_bit_cast(s16x8, pk);
    }
  };
  auto stageB = [&](int ks, int buf) __attribute__((always_inline)) {
    const long pan = (long)(ct2 * 32 + ks) * 16384;
#pragma unroll
    for (int i = 0; i < 4; i++) {
      int gb = w * 4 + i;  // 32 groups, 8 waves x 4
      const short* src = Bg + pan + gb * 512 + l * 8;
      gload_lds16(src, lds + buf * 18432 + 2048 + gb * 512);
    }
  };

  const unsigned lds0 = lds_addr(lds);
  auto process = [&](int buf) __attribute__((always_inline)) {
    const unsigned lbase = lds0 + buf * 36864u;
    const unsigned aswz = (quad * 16 + (lm ^ (quad * 2))) * 16;
    s16x8 af[4], bfr[4];
#pragma unroll
    for (int mi = 0; mi < 4; mi++)
      af[mi] = ds_read_b128a(lbase + mi * 1024 + aswz);
#pragma unroll
    for (int ni = 0; ni < 4; ni++)
      bfr[ni] = ds_read_b128a(lbase + 4096 + (w * 4 + ni) * 1024 + l * 16);
    WAIT_LGKM0();  // asm reads done; MFMAs can't hoist above (rule #18)
    __builtin_amdgcn_s_setprio(1);
#pragma unroll
    for (int mi = 0; mi < 4; mi++)
#pragma unroll
      for (int ni = 0; ni < 4; ni++)
        acc[mi][ni] = mfma_bf16(af[mi], bfr[ni], acc[mi][ni]);
    __builtin_amdgcn_s_setprio(0);
  };

  loadA(0);
  stageB(0, 0);
  writeA(0);
  __syncthreads();
  int cur = 0;
  for (int ks = 0; ks < 32; ++ks) {
    if (ks + 1 < 32) { loadA(ks + 1); stageB(ks + 1, cur ^ 1); }
    SCHED0();
    process(cur);
    if (ks + 1 < 32) writeA(cur ^ 1);  // A regs landed under process
    __syncthreads();
    cur ^= 1;
  }

  const int rowbase = row0;            // 64-row tile, multiple of 64
  const int colbase = col0 + w * 64;   // wave w: single head
  const int b = rowbase >> 11;
  const int h = colbase >> 6;
  const int rloc = rowbase & 2047;
  if (z == 0) {
    const float osc = 0.0450842200277801f;  // log2(e)/sqrt(1024)
    long base = ((long)(b * HEADS + h)) * NSEQ * HD;
    for (int mi = 0; mi < 4; mi++)
      for (int r = 0; r < 4; r++) {
        int q = rloc + mi * 16 + quad * 4 + r;
        long rowoff = base + (long)q * HD + lm;
        for (int ni = 0; ni < 4; ni++)
          Qh[rowoff + ni * 16] = f2bf(acc[mi][ni][r] * osc);
      }
  } else if (z == 1) {
    // K chunks: group s*4+j*2+c, lane quadk*16+lmk, elem ek.
    long bhb = ((long)(b * HEADS + h)) * 262144;
    for (int mi = 0; mi < 4; mi++)
      for (int r = 0; r < 4; r++) {
        int q = rloc + mi * 16 + quad * 4 + r;
        int tile = q >> 7, s = (q >> 5) & 3, jj = (q >> 4) & 1, lmk = q & 15;
        for (int ni = 0; ni < 4; ni++) {
          int c = ni >> 1, quadk = (ni * 2 + (lm >> 3)) & 3, ek = lm & 7;
          long addr = bhb + (long)tile * 16384 + (s * 4 + jj * 2 + c) * 512 +
                      (quadk * 16 + lmk) * 8 + ek;
          KVg[addr] = f2bf(acc[mi][ni][r]);
        }
      }
  } else {
    // V chunks (interleaved keys): group 16+s*4+ni, lane quad*16+lm, elem ev.
    long bhb = ((long)(b * HEADS + h)) * 262144;
    for (int mi = 0; mi < 4; mi++)
      for (int r = 0; r < 4; r++) {
        int kc = rloc + (mi >> 1) * 32 + quad * 8 + (mi & 1) * 4 + r;
        int tile = kc >> 7, s = (kc >> 5) & 3, ev = (mi & 1) * 4 + r;
        for (int ni = 0; ni < 4; ni++) {
          long addr = bhb + (long)tile * 16384 + (16 + s * 4 + ni) * 512 +
                      (quad * 16 + lm) * 8 + ev;
          KVg[addr] = f2bf(acc[mi][ni][r]);
        }
      }
  }
}

// ---------------------------------------------------------------------------
// 3) Transposed-S flash attention. Grid (bh=64, qy=16) -> XCD = bh%8.
//    4 waves, wave = 32 q-rows; 128-key tiles staged from KVg with CONTIGUOUS
//    1KB gload_lds (8/wave/tile). Unchanged.
__global__ __launch_bounds__(256, 2) void attn_kernel(
    const short* __restrict__ Qh, const short* __restrict__ KVg,
    short* __restrict__ Obf) {
  __shared__ short lds[2 * 16384];
  const int t = threadIdx.x;
  const int w = t >> 6, l = t & 63, quad = l >> 4, lm = l & 15;
  const int bh = blockIdx.x;
  const int qtile = blockIdx.y * 128 + w * 32;
  const short* Qp  = Qh  + (long)bh * NSEQ * HD;
  const short* KVp = KVg + (long)bh * 262144;

  s16x8 aq[2][2];
#pragma unroll
  for (int qi = 0; qi < 2; qi++)
#pragma unroll
    for (int c = 0; c < 2; c++)
      aq[qi][c] = *(const s16x8*)(Qp + (long)(qtile + qi * 16 + lm) * HD + c * 32 + quad * 8);

  floatx4 acc[2][4];
  float lsum[2] = {0.f, 0.f};
#pragma unroll
  for (int qi = 0; qi < 2; qi++)
#pragma unroll
    for (int n = 0; n < 4; n++) acc[qi][n] = (floatx4){0.f, 0.f, 0.f, 0.f};

  auto stage = [&](int kt, int buf) __attribute__((always_inline)) {
    short* base = lds + buf * 16384;
    const short* tsrc = KVp + (long)(kt >> 7) * 16384;
#pragma unroll
    for (int i = 0; i < 8; i++) {
      int g = w * 8 + i;
      gload_lds16(tsrc + g * 512 + l * 8, base + g * 512);  // contiguous 1KB
    }
  };

  auto process = [&](const short* Lb, int s) __attribute__((always_inline)) {
    s16x8 bk[2][2];
#pragma unroll
    for (int j = 0; j < 2; j++)
#pragma unroll
      for (int c = 0; c < 2; c++)
        bk[j][c] = *(const s16x8*)(Lb + ((s * 4 + j * 2 + c) * 64 + l) * 8);
    s16x8 vraw[4];
#pragma unroll
    for (int n = 0; n < 4; n++)
      vraw[n] = *(const s16x8*)(Lb + ((16 + s * 4 + n) * 64 + l) * 8);
#pragma unroll
    for (int qi = 0; qi < 2; qi++) {
      floatx4 sT[2];
      sT[0] = (floatx4){0.f, 0.f, 0.f, 0.f};
      sT[1] = (floatx4){0.f, 0.f, 0.f, 0.f};
      __builtin_amdgcn_s_setprio(1);
#pragma unroll
      for (int c = 0; c < 2; c++) {
        sT[0] = mfma_bf16(bk[0][c], aq[qi][c], sT[0]);
        sT[1] = mfma_bf16(bk[1][c], aq[qi][c], sT[1]);
      }
      __builtin_amdgcn_s_setprio(0);
      float p0 = __builtin_amdgcn_exp2f(sT[0][0]);
      float p1 = __builtin_amdgcn_exp2f(sT[0][1]);
      float p2 = __builtin_amdgcn_exp2f(sT[0][2]);
      float p3 = __builtin_amdgcn_exp2f(sT[0][3]);
      float p4 = __builtin_amdgcn_exp2f(sT[1][0]);
      float p5 = __builtin_amdgcn_exp2f(sT[1][1]);
      float p6 = __builtin_amdgcn_exp2f(sT[1][2]);
      float p7 = __builtin_amdgcn_exp2f(sT[1][3]);
      lsum[qi] += ((p0 + p1) + (p2 + p3)) + ((p4 + p5) + (p6 + p7));
      u32x4 pw = {pack2_bf16(p0, p1), pack2_bf16(p2, p3),
                  pack2_bf16(p4, p5), pack2_bf16(p6, p7)};
      s16x8 pcat = __builtin_bit_cast(s16x8, pw);
      __builtin_amdgcn_s_setprio(1);
#pragma unroll
      for (int n = 0; n < 4; n++)
        acc[qi][n] = mfma_bf16(vraw[n], pcat, acc[qi][n]);
      __builtin_amdgcn_s_setprio(0);
    }
  };

  stage(0, 0);
  __syncthreads();
  int cur = 0;
  for (int kt = 0; kt < NSEQ; kt += 128) {
    if (kt + 128 < NSEQ) stage(kt + 128, cur ^ 1);
    const short* Lb = lds + cur * 16384;
    process(Lb, 0);
    process(Lb, 1);
    process(Lb, 2);
    process(Lb, 3);
    __syncthreads();
    cur ^= 1;
  }

  const int b = bh >> 4, h = bh & 15;
  short* Ow = lds + w * 1152;  // buf0 region; final tile was read from buf1
  const int erow = l >> 2, ecg = l & 3;
#pragma unroll
  for (int qi = 0; qi < 2; qi++) {
    float ls = lsum[qi];
    ls += __shfl_xor(ls, 16);
    ls += __shfl_xor(ls, 32);
    float rl = 1.0f / ls;
#pragma unroll
    for (int n = 0; n < 4; n++)
#pragma unroll
      for (int r = 0; r < 4; r++)
        Ow[lm * 72 + n * 16 + quad * 4 + r] = f2bf(acc[qi][n][r] * rl);
    s16x8 o0 = *(const s16x8*)(Ow + erow * 72 + ecg * 16);
    s16x8 o1 = *(const s16x8*)(Ow + erow * 72 + ecg * 16 + 8);
    long gaddr = ((long)(b * NSEQ + qtile + qi * 16 + erow)) * DM + h * HD + ecg * 16;
    *(s16x8*)(Obf + gaddr) = o0;
    *(s16x8*)(Obf + gaddr + 8) = o1;
  }
}

// ---------------------------------------------------------------------------
// 4) Output GEMM: d_out = Obf(bf16) @ Wo + bo. 128x128, BK=32, 256thr.
//    3 x 16KiB buffers; B 2-deep counted pipeline; A reg-staged coalesced +
//    swizzled ds_write (1-deep). Unchanged from R17 (verified).
__global__ __launch_bounds__(256, 2) void out_kernel(
    const short* __restrict__ Ab, const short* __restrict__ WoG,
    const float* __restrict__ bias, float* __restrict__ Out) {
  __shared__ short lds[3 * 8192];
  const int t = threadIdx.x;
  const int w = t >> 6, l = t & 63, quad = l >> 4, lm = l & 15;
  const int wm = w >> 1, wn = w & 1;
  const int row0 = blockIdx.x * 128;
  const int ct = blockIdx.y;
  const int col0 = ct * 128;

  floatx4 acc[4][4];
  for (int mi = 0; mi < 4; mi++)
    for (int ni = 0; ni < 4; ni++) acc[mi][ni] = (floatx4){0.f, 0.f, 0.f, 0.f};

  s16x8 ar[2];
  auto loadA = [&](int kt) __attribute__((always_inline)) {
#pragma unroll
    for (int j = 0; j < 2; j++) {
      int tt = j * 256 + t, r = tt >> 2, c = tt & 3;
      ar[j] = *(const s16x8*)(Ab + (long)(row0 + r) * DM + kt * 32 + c * 8);
    }
  };
  auto writeA = [&](int buf) __attribute__((always_inline)) {
#pragma unroll
    for (int j = 0; j < 2; j++) {
      int tt = j * 256 + t, r = tt >> 2, q4 = tt & 3;
      int lm2 = r & 15, g16 = r >> 4;
      int l3 = q4 * 16 + (lm2 ^ (q4 * 2));
      *(s16x8*)(lds + buf * 8192 + g16 * 512 + l3 * 8) = ar[j];
    }
  };
  auto stageB = [&](int kt, int buf) __attribute__((always_inline)) {
    const long pan = ((long)(ct * 16 + (kt >> 1))) * 8192;
    const int kk = kt & 1;
#pragma unroll
    for (int i = 0; i < 2; i++) {
      int gb = w * 2 + i;  // 8 groups, 4 waves x 2
      const short* src = WoG + pan + (gb * 2 + kk) * 512 + l * 8;
      gload_lds16(src, lds + buf * 8192 + 4096 + gb * 512);
    }
  };
  const unsigned lds0 = lds_addr(lds);
  auto process = [&](int buf) __attribute__((always_inline)) {
    const unsigned lbase = lds0 + buf * 16384;
    const unsigned aswz = (quad * 16 + (lm ^ (quad * 2))) * 16;
    s16x8 af[4], bfr[4];
#pragma unroll
    for (int mi = 0; mi < 4; mi++)
      af[mi] = ds_read_b128a(lbase + (wm * 4 + mi) * 1024 + aswz);
#pragma unroll
    for (int ni = 0; ni < 4; ni++)
      bfr[ni] = ds_read_b128a(lbase + 8192 + (wn * 4 + ni) * 1024 + l * 16);
    WAIT_LGKM0();
    __builtin_amdgcn_s_setprio(1);
#pragma unroll
    for (int mi = 0; mi < 4; mi++)
#pragma unroll
      for (int ni = 0; ni < 4; ni++)
        acc[mi][ni] = mfma_bf16(af[mi], bfr[ni], acc[mi][ni]);
    __builtin_amdgcn_s_setprio(0);
  };

  loadA(0);
  stageB(0, 0);
  stageB(1, 1);
  writeA(0);        // implicit wait for A(0) regs (B0,B1 stay in flight)
  WAIT_VMCNT(2);    // B(0) landed (B(1) outstanding)
  WAIT_LGKM0();
  __builtin_amdgcn_s_barrier();

  for (int kt = 0; kt < 32; ++kt) {
    if (kt + 1 < 32) loadA(kt + 1);
    if (kt + 2 < 32) stageB(kt + 2, (kt + 2) % 3);
    SCHED0();
    process(kt % 3);
    if (kt + 1 < 32) writeA((kt + 1) % 3);
    WAIT_VMCNT(2);
    WAIT_LGKM0();
    __builtin_amdgcn_s_barrier();
  }

  const int rowbase = row0 + wm * 64;
  const int colbase = col0 + wn * 64;
  for (int mi = 0; mi < 4; mi++)
    for (int r = 0; r < 4; r++) {
      int gr = rowbase + mi * 16 + quad * 4 + r;
      for (int ni = 0; ni < 4; ni++) {
        int gc = colbase + ni * 16 + lm;
        Out[(long)gr * DM + gc] = acc[mi][ni][r] + bias[gc];
      }
    }
}

// ---------------------------------------------------------------------------
extern "C" void kernel_launch(void* const* d_in, const int* in_sizes, int n_in,
                              void* d_out, int out_size, void* d_ws, size_t ws_size,
                              hipStream_t stream) {
  (void)in_sizes; (void)n_in; (void)out_size; (void)ws_size;
  const float* queries = (const float*)d_in[0];
  const float* keys    = (const float*)d_in[1];
  const float* values  = (const float*)d_in[2];
  const float* Wq = (const float*)d_in[3];
  const float* Wk = (const float*)d_in[4];
  const float* Wv = (const float*)d_in[5];
  const float* Wo = (const float*)d_in[6];
  const float* bo = (const float*)d_in[7];
  float* out = (float*)d_out;

  char* ws = (char*)d_ws;
  const size_t MB = 1024 * 1024;
  short* WqG = (short*)(ws + 0 * MB);   // 2 MiB each (group layout)
  short* WkG = (short*)(ws + 2 * MB);
  short* WvG = (short*)(ws + 4 * MB);
  short* WoG = (short*)(ws + 6 * MB);
  short* Qh  = (short*)(ws + 8 * MB);   // [B,H,2048,64] bf16 = 16 MiB
  short* KVg = (short*)(ws + 24 * MB);  // [bh][16 tiles][32 groups][64][8] = 32 MiB
  short* Obf = (short*)(ws + 56 * MB);  // [8192,1024] bf16 = 16 MiB (total 72)

  make_wgroups<<<dim3(16, 16, 4), 256, 0, stream>>>(
      Wq, Wk, Wv, Wo, WqG, WkG, WvG, WoG);
  proj_kernel<<<dim3(128, 2, 3), 512, 0, stream>>>(
      queries, keys, values, WqG, WkG, WvG, Qh, KVg);
  attn_kernel<<<dim3(64, 16), 256, 0, stream>>>(Qh, KVg, Obf);
  out_kernel<<<dim3(64, 8), 256, 0, stream>>>(Obf, WoG, bo, out);
}

// Round 14
// 318.928 us; speedup vs baseline: 1.0448x; 1.0448x over previous
//
#include <hip/hip_runtime.h>

// ScaledDotProductAttention: B=4, NQ=NK=2048, D_MODEL=D_K=D_V=1024, H=16, HD=64.
// R19: proj reverted to its BEST VERIFIED config (R14: BM128/BN256/BK64,
// 2-phase, 108us; seven sync variants + three tile shapes all bracket proj at
// 108-130 -> structural floor at 1 block/CU, stop burning rounds there).
// This round's single change: attn Q-tile 128->256 rows/block (8 waves, grid
// qy 16->8) -> KV re-staging traffic halves (512MB->256MB) and waves/CU
// double (8->16). Per-wave math unchanged.
//  1) make_wgroups : W* -> fragment-GROUP layout (R14 BN256/BK64 panels).
//  2) proj_kernel  : 128x256, BK=64, 512thr, 2x48KB, R14 2-phase (verified).
//  3) attn_kernel  : 8 waves/block, 256 q-rows, KVg contiguous staging,
//                    128-key tiles, 2 blocks/CU.
//  4) out_kernel   : R17 counted template (verified).
// Workspace 72 MiB: Wg 4x2MB | Qh 16MB | KVg 32MB | Obf 16MB.

#define DM    1024
#define NSEQ  2048
#define HEADS 16
#define HD    64

typedef float floatx4 __attribute__((ext_vector_type(4)));
typedef short s16x4   __attribute__((ext_vector_type(4)));
typedef short s16x8   __attribute__((ext_vector_type(8)));
typedef unsigned int u32x4 __attribute__((ext_vector_type(4)));

static __device__ __forceinline__ floatx4 mfma_bf16(s16x8 a, s16x8 b, floatx4 c) {
  return __builtin_amdgcn_mfma_f32_16x16x32_bf16(a, b, c, 0, 0, 0);
}

// Async global->LDS DMA, 16B per lane: dest = wave-uniform base + lane*16,
// source = per-lane global address (contiguous 1KB per instruction here).
static __device__ __forceinline__ void gload_lds16(const void* g, void* l) {
  __builtin_amdgcn_global_load_lds(
      (const __attribute__((address_space(1))) unsigned*)g,
      (__attribute__((address_space(3))) unsigned*)l, 16, 0, 0);
}

static __device__ __forceinline__ unsigned lds_addr(const void* p) {
  return (unsigned)(unsigned long long)p;
}

// Inline-asm ds_read_b128 (opaque to alias analysis -> no compiler-inserted
// vmcnt(0) drain; caller fences with lgkmcnt(0)+sched_barrier per rule #18).
static __device__ __forceinline__ s16x8 ds_read_b128a(unsigned byteaddr) {
  s16x8 r;
  asm volatile("ds_read_b128 %0, %1" : "=v"(r) : "v"(byteaddr));
  return r;
}

#define SCHED0() __builtin_amdgcn_sched_barrier(0)
#define WAIT_LGKM0() \
  { asm volatile("s_waitcnt lgkmcnt(0)" ::: "memory"); __builtin_amdgcn_sched_barrier(0); }
#define WAIT_VMCNT(N) \
  { asm volatile("s_waitcnt vmcnt(" #N ")" ::: "memory"); __builtin_amdgcn_sched_barrier(0); }

// fp32 -> bf16 round-to-nearest-even (bit trick; inputs are finite)
static __device__ __forceinline__ short f2bf(float f) {
  unsigned u = __builtin_bit_cast(unsigned, f);
  u += 0x7FFFu + ((u >> 16) & 1u);
  return (short)(u >> 16);
}

// Packed fp32 pair -> 2 bf16 (RNE, same result as f2bf) in one VALU op.
static __device__ __forceinline__ unsigned cvtpk_bf16(float lo, float hi) {
  unsigned r;
  asm("v_cvt_pk_bf16_f32 %0, %1, %2" : "=v"(r) : "v"(lo), "v"(hi));
  return r;
}

// Pack 2 fp32 -> 2 bf16 in one u32 (round-half-up; attn P-values only).
static __device__ __forceinline__ unsigned pack2_bf16(float a, float b) {
  unsigned ua = __builtin_bit_cast(unsigned, a) + 0x8000u;
  unsigned ub = __builtin_bit_cast(unsigned, b) + 0x8000u;
#if __has_builtin(__builtin_amdgcn_perm)
  return __builtin_amdgcn_perm(ub, ua, 0x07060302u);
#else
  return (ub & 0xffff0000u) | (ua >> 16);
#endif
}

// ---------------------------------------------------------------------------
// 1) Weights -> fragment-group layout (R14).
//    Chunk definition: group g=(g16*2+kk), lane l'=(quad*16+lm), 8 shorts e:
//    W^T[ntile_base + g16*16+lm][ks*64 + kk*32 + quad*8 + e].
//    BN256 (Wq,Wk,Wv): panel (ct 0..3, ks 0..15) = 32 groups at
//    (ct*16+ks)*16384. BN128 (Wo): (ct 0..7): 16 groups at (ct*16+ks)*8192.
__global__ __launch_bounds__(256) void make_wgroups(
    const float* __restrict__ W0, const float* __restrict__ W1,
    const float* __restrict__ W2, const float* __restrict__ W3,
    short* __restrict__ G0, short* __restrict__ G1,
    short* __restrict__ G2, short* __restrict__ G3) {
  __shared__ float tile[64][68];  // [k][n], padded
  const int m = blockIdx.z;
  const float* W = m == 0 ? W0 : m == 1 ? W1 : m == 2 ? W2 : W3;
  short*       G = m == 0 ? G0 : m == 1 ? G1 : m == 2 ? G2 : G3;
  const int nt = blockIdx.x, kt = blockIdx.y;  // 16 x 16 tiles of 64x64
  const int n0 = nt * 64, k0 = kt * 64;
  const int t = threadIdx.x;
  for (int j = 0; j < 4; j++) {
    int idx = j * 256 + t, r = idx >> 4, cq = idx & 15;
    *(floatx4*)&tile[r][cq * 4] = *(const floatx4*)(W + (long)(k0 + r) * DM + n0 + cq * 4);
  }
  __syncthreads();
  for (int j = 0; j < 2; j++) {
    int ci = j * 256 + t;
    int lm = ci & 15, quad = (ci >> 4) & 3, kk = (ci >> 6) & 1, gl = ci >> 7;
    s16x8 v;
#pragma unroll
    for (int e = 0; e < 8; e++) v[e] = f2bf(tile[kk * 32 + quad * 8 + e][gl * 16 + lm]);
    long addr;
    if (m < 3) {
      int ct = nt >> 2, g16 = (nt & 3) * 4 + gl;
      addr = ((long)(ct * 16 + kt)) * 16384 + (g16 * 2 + kk) * 512 + (quad * 16 + lm) * 8;
    } else {
      int ct = nt >> 1, g16 = (nt & 1) * 4 + gl;
      addr = ((long)(ct * 16 + kt)) * 8192 + (g16 * 2 + kk) * 512 + (quad * 16 + lm) * 8;
    }
    *(s16x8*)(G + addr) = v;
  }
}

// ---------------------------------------------------------------------------
// 2) Projection GEMM (R14, verified 108us): C[8192x1024] = A(fp32) @ W.
//    128x256 tile, BK=64, 512thr. Per 48KiB buffer: A bf16 16 groups x 1KiB
//    (g16*2+kk) at byte g*1024, swizzled slot q4*16+(lm2^(q4*2)); B bf16 32
//    groups at byte 16384+gb*1024, linear (one Wg panel per step).
//    z=0:->Qh (PRE-SCALED log2e/sqrt(1024)), z=1: K->KVg 0..15, z=2: V->KVg
//    16..31 (interleaved keys).
__global__ __launch_bounds__(512, 2) void proj_kernel(
    const float* __restrict__ Aq, const float* __restrict__ Ak, const float* __restrict__ Av,
    const short* __restrict__ BgQ, const short* __restrict__ BgK, const short* __restrict__ BgV,
    short* __restrict__ Qh, short* __restrict__ KVg) {
  __shared__ short lds[2 * 24576];  // 2 x 48 KiB
  const int z = blockIdx.z;
  const float* A  = z == 0 ? Aq  : z == 1 ? Ak  : Av;
  const short* Bg = z == 0 ? BgQ : z == 1 ? BgK : BgV;
  const int t = threadIdx.x;
  const int w = t >> 6, l = t & 63, quad = l >> 4, lm = l & 15;
  const int wm = w >> 2, wn = w & 3;  // 2 row-waves x 4 col-waves
  const int row0 = blockIdx.x * 128;
  const int ct = blockIdx.y;          // 256-col tile
  const int col0 = ct * 256;

  floatx4 acc[4][4];
  for (int mi = 0; mi < 4; mi++)
    for (int ni = 0; ni < 4; ni++) acc[mi][ni] = (floatx4){0.f, 0.f, 0.f, 0.f};

  // A reg-stage: thread covers chunks tt = j*512+t (j=0,1): row r=tt>>3,
  // 8 floats at (tt&7)*8 -- 256B coalesced runs, 8 lanes/row.
  floatx4 ar[2][2];
  auto loadA = [&](int ks) __attribute__((always_inline)) {
#pragma unroll
    for (int j = 0; j < 2; j++) {
      int tt = j * 512 + t, r = tt >> 3, c8 = (tt & 7) * 8;
      const float* p = A + (long)(row0 + r) * DM + ks * 64 + c8;
      ar[j][0] = *(const floatx4*)p;
      ar[j][1] = *(const floatx4*)(p + 4);
    }
  };
  auto writeA = [&](int buf) __attribute__((always_inline)) {
#pragma unroll
    for (int j = 0; j < 2; j++) {
      int tt = j * 512 + t, r = tt >> 3;
      int kk = (tt & 7) >> 2, q4 = tt & 3, lm2 = r & 15, g16 = r >> 4;
      u32x4 pk = {cvtpk_bf16(ar[j][0][0], ar[j][0][1]), cvtpk_bf16(ar[j][0][2], ar[j][0][3]),
                  cvtpk_bf16(ar[j][1][0], ar[j][1][1]), cvtpk_bf16(ar[j][1][2], ar[j][1][3])};
      int l3 = q4 * 16 + (lm2 ^ (q4 * 2));  // XOR swizzle: 2-way max both sides
      *(s16x8*)(lds + buf * 24576 + (g16 * 2 + kk) * 512 + l3 * 8) =
          __builtin_bit_cast(s16x8, pk);
    }
  };
  auto stageB = [&](int ks, int buf) __attribute__((always_inline)) {
    const long pan = ((long)(ct * 16 + ks)) * 16384;
#pragma unroll
    for (int i = 0; i < 4; i++) {
      int gb = w * 4 + i;  // 32 groups, 8 waves x 4
      const short* src = Bg + pan + gb * 512 + l * 8;
      gload_lds16(src, lds + buf * 24576 + 8192 + gb * 512);
    }
  };

  const unsigned lds0 = lds_addr(lds);
  auto process = [&](int buf) __attribute__((always_inline)) {
    const unsigned lbase = lds0 + buf * 49152u;
    const unsigned aswz = (quad * 16 + (lm ^ (quad * 2))) * 16;
#pragma unroll
    for (int kk = 0; kk < 2; kk++) {
      s16x8 af[4], bfr[4];
#pragma unroll
      for (int mi = 0; mi < 4; mi++)
        af[mi] = ds_read_b128a(lbase + ((wm * 4 + mi) * 2 + kk) * 1024 + aswz);
#pragma unroll
      for (int ni = 0; ni < 4; ni++)
        bfr[ni] = ds_read_b128a(lbase + 16384 + ((wn * 4 + ni) * 2 + kk) * 1024 + l * 16);
      WAIT_LGKM0();  // asm reads done; MFMAs can't hoist above (rule #18)
      __builtin_amdgcn_s_setprio(1);
#pragma unroll
      for (int mi = 0; mi < 4; mi++)
#pragma unroll
        for (int ni = 0; ni < 4; ni++)
          acc[mi][ni] = mfma_bf16(af[mi], bfr[ni], acc[mi][ni]);
      __builtin_amdgcn_s_setprio(0);
    }
  };

  loadA(0);
  stageB(0, 0);
  writeA(0);
  __syncthreads();
  int cur = 0;
  for (int ks = 0; ks < 16; ++ks) {
    if (ks + 1 < 16) { loadA(ks + 1); stageB(ks + 1, cur ^ 1); }
    SCHED0();
    process(cur);
    if (ks + 1 < 16) writeA(cur ^ 1);  // A regs landed under process
    __syncthreads();
    cur ^= 1;
  }

  const int rowbase = row0 + wm * 64;
  const int colbase = col0 + wn * 64;
  const int b = rowbase >> 11;
  const int h = colbase >> 6;
  const int rloc = rowbase & 2047;
  if (z == 0) {
    const float osc = 0.0450842200277801f;  // log2(e)/sqrt(1024)
    long base = ((long)(b * HEADS + h)) * NSEQ * HD;
    for (int mi = 0; mi < 4; mi++)
      for (int r = 0; r < 4; r++) {
        int q = rloc + mi * 16 + quad * 4 + r;
        long rowoff = base + (long)q * HD + lm;
        for (int ni = 0; ni < 4; ni++)
          Qh[rowoff + ni * 16] = f2bf(acc[mi][ni][r] * osc);
      }
  } else if (z == 1) {
    // K chunks: group s*4+j*2+c, lane quadk*16+lmk, elem ek.
    long bhb = ((long)(b * HEADS + h)) * 262144;
    for (int mi = 0; mi < 4; mi++)
      for (int r = 0; r < 4; r++) {
        int q = rloc + mi * 16 + quad * 4 + r;
        int tile = q >> 7, s = (q >> 5) & 3, jj = (q >> 4) & 1, lmk = q & 15;
        for (int ni = 0; ni < 4; ni++) {
          int c = ni >> 1, quadk = (ni * 2 + (lm >> 3)) & 3, ek = lm & 7;
          long addr = bhb + (long)tile * 16384 + (s * 4 + jj * 2 + c) * 512 +
                      (quadk * 16 + lmk) * 8 + ek;
          KVg[addr] = f2bf(acc[mi][ni][r]);
        }
      }
  } else {
    // V chunks (interleaved keys): group 16+s*4+ni, lane quad*16+lm, elem ev.
    long bhb = ((long)(b * HEADS + h)) * 262144;
    for (int mi = 0; mi < 4; mi++)
      for (int r = 0; r < 4; r++) {
        int kc = rloc + (mi >> 1) * 32 + quad * 8 + (mi & 1) * 4 + r;
        int tile = kc >> 7, s = (kc >> 5) & 3, ev = (mi & 1) * 4 + r;
        for (int ni = 0; ni < 4; ni++) {
          long addr = bhb + (long)tile * 16384 + (16 + s * 4 + ni) * 512 +
                      (quad * 16 + lm) * 8 + ev;
          KVg[addr] = f2bf(acc[mi][ni][r]);
        }
      }
  }
}

// ---------------------------------------------------------------------------
// 3) Transposed-S flash attention. R19: 8 waves/block (512 thr), 256 q-rows
//    per block, grid (bh=64, qy=8) -> KV re-staging traffic halved and
//    16 waves/CU. Per-wave math unchanged (wave = 32 q-rows). 128-key tiles
//    staged from KVg with CONTIGUOUS 1KB gload_lds (4/wave/tile, 32 groups).
__global__ __launch_bounds__(512, 2) void attn_kernel(
    const short* __restrict__ Qh, const short* __restrict__ KVg,
    short* __restrict__ Obf) {
  __shared__ short lds[2 * 16384];
  const int t = threadIdx.x;
  const int w = t >> 6, l = t & 63, quad = l >> 4, lm = l & 15;
  const int bh = blockIdx.x;
  const int qtile = blockIdx.y * 256 + w * 32;
  const short* Qp  = Qh  + (long)bh * NSEQ * HD;
  const short* KVp = KVg + (long)bh * 262144;

  s16x8 aq[2][2];
#pragma unroll
  for (int qi = 0; qi < 2; qi++)
#pragma unroll
    for (int c = 0; c < 2; c++)
      aq[qi][c] = *(const s16x8*)(Qp + (long)(qtile + qi * 16 + lm) * HD + c * 32 + quad * 8);

  floatx4 acc[2][4];
  float lsum[2] = {0.f, 0.f};
#pragma unroll
  for (int qi = 0; qi < 2; qi++)
#pragma unroll
    for (int n = 0; n < 4; n++) acc[qi][n] = (floatx4){0.f, 0.f, 0.f, 0.f};

  auto stage = [&](int kt, int buf) __attribute__((always_inline)) {
    short* base = lds + buf * 16384;
    const short* tsrc = KVp + (long)(kt >> 7) * 16384;
#pragma unroll
    for (int i = 0; i < 4; i++) {
      int g = w * 4 + i;  // 32 groups over 8 waves
      gload_lds16(tsrc + g * 512 + l * 8, base + g * 512);  // contiguous 1KB
    }
  };

  auto process = [&](const short* Lb, int s) __attribute__((always_inline)) {
    s16x8 bk[2][2];
#pragma unroll
    for (int j = 0; j < 2; j++)
#pragma unroll
      for (int c = 0; c < 2; c++)
        bk[j][c] = *(const s16x8*)(Lb + ((s * 4 + j * 2 + c) * 64 + l) * 8);
    s16x8 vraw[4];
#pragma unroll
    for (int n = 0; n < 4; n++)
      vraw[n] = *(const s16x8*)(Lb + ((16 + s * 4 + n) * 64 + l) * 8);
#pragma unroll
    for (int qi = 0; qi < 2; qi++) {
      floatx4 sT[2];
      sT[0] = (floatx4){0.f, 0.f, 0.f, 0.f};
      sT[1] = (floatx4){0.f, 0.f, 0.f, 0.f};
      __builtin_amdgcn_s_setprio(1);
#pragma unroll
      for (int c = 0; c < 2; c++) {
        sT[0] = mfma_bf16(bk[0][c], aq[qi][c], sT[0]);
        sT[1] = mfma_bf16(bk[1][c], aq[qi][c], sT[1]);
      }
      __builtin_amdgcn_s_setprio(0);
      float p0 = __builtin_amdgcn_exp2f(sT[0][0]);
      float p1 = __builtin_amdgcn_exp2f(sT[0][1]);
      float p2 = __builtin_amdgcn_exp2f(sT[0][2]);
      float p3 = __builtin_amdgcn_exp2f(sT[0][3]);
      float p4 = __builtin_amdgcn_exp2f(sT[1][0]);
      float p5 = __builtin_amdgcn_exp2f(sT[1][1]);
      float p6 = __builtin_amdgcn_exp2f(sT[1][2]);
      float p7 = __builtin_amdgcn_exp2f(sT[1][3]);
      lsum[qi] += ((p0 + p1) + (p2 + p3)) + ((p4 + p5) + (p6 + p7));
      u32x4 pw = {pack2_bf16(p0, p1), pack2_bf16(p2, p3),
                  pack2_bf16(p4, p5), pack2_bf16(p6, p7)};
      s16x8 pcat = __builtin_bit_cast(s16x8, pw);
      __builtin_amdgcn_s_setprio(1);
#pragma unroll
      for (int n = 0; n < 4; n++)
        acc[qi][n] = mfma_bf16(vraw[n], pcat, acc[qi][n]);
      __builtin_amdgcn_s_setprio(0);
    }
  };

  stage(0, 0);
  __syncthreads();
  int cur = 0;
  for (int kt = 0; kt < NSEQ; kt += 128) {
    if (kt + 128 < NSEQ) stage(kt + 128, cur ^ 1);
    const short* Lb = lds + cur * 16384;
    process(Lb, 0);
    process(Lb, 1);
    process(Lb, 2);
    process(Lb, 3);
    __syncthreads();
    cur ^= 1;
  }

  const int b = bh >> 4, h = bh & 15;
  short* Ow = lds + w * 1152;  // 8 waves x 1152 = 9216 shorts, fits buf0;
  const int erow = l >> 2, ecg = l & 3;  // last tile was read from buf1
#pragma unroll
  for (int qi = 0; qi < 2; qi++) {
    float ls = lsum[qi];
    ls += __shfl_xor(ls, 16);
    ls += __shfl_xor(ls, 32);
    float rl = 1.0f / ls;
#pragma unroll
    for (int n = 0; n < 4; n++)
#pragma unroll
      for (int r = 0; r < 4; r++)
        Ow[lm * 72 + n * 16 + quad * 4 + r] = f2bf(acc[qi][n][r] * rl);
    s16x8 o0 = *(const s16x8*)(Ow + erow * 72 + ecg * 16);
    s16x8 o1 = *(const s16x8*)(Ow + erow * 72 + ecg * 16 + 8);
    long gaddr = ((long)(b * NSEQ + qtile + qi * 16 + erow)) * DM + h * HD + ecg * 16;
    *(s16x8*)(Obf + gaddr) = o0;
    *(s16x8*)(Obf + gaddr + 8) = o1;
  }
}

// ---------------------------------------------------------------------------
// 4) Output GEMM: d_out = Obf(bf16) @ Wo + bo. 128x128, BK=32, 256thr.
//    3 x 16KiB buffers; B 2-deep counted pipeline; A reg-staged coalesced +
//    swizzled ds_write (1-deep). Unchanged from R17 (verified).
__global__ __launch_bounds__(256, 2) void out_kernel(
    const short* __restrict__ Ab, const short* __restrict__ WoG,
    const float* __restrict__ bias, float* __restrict__ Out) {
  __shared__ short lds[3 * 8192];
  const int t = threadIdx.x;
  const int w = t >> 6, l = t & 63, quad = l >> 4, lm = l & 15;
  const int wm = w >> 1, wn = w & 1;
  const int row0 = blockIdx.x * 128;
  const int ct = blockIdx.y;
  const int col0 = ct * 128;

  floatx4 acc[4][4];
  for (int mi = 0; mi < 4; mi++)
    for (int ni = 0; ni < 4; ni++) acc[mi][ni] = (floatx4){0.f, 0.f, 0.f, 0.f};

  s16x8 ar[2];
  auto loadA = [&](int kt) __attribute__((always_inline)) {
#pragma unroll
    for (int j = 0; j < 2; j++) {
      int tt = j * 256 + t, r = tt >> 2, c = tt & 3;
      ar[j] = *(const s16x8*)(Ab + (long)(row0 + r) * DM + kt * 32 + c * 8);
    }
  };
  auto writeA = [&](int buf) __attribute__((always_inline)) {
#pragma unroll
    for (int j = 0; j < 2; j++) {
      int tt = j * 256 + t, r = tt >> 2, q4 = tt & 3;
      int lm2 = r & 15, g16 = r >> 4;
      int l3 = q4 * 16 + (lm2 ^ (q4 * 2));
      *(s16x8*)(lds + buf * 8192 + g16 * 512 + l3 * 8) = ar[j];
    }
  };
  auto stageB = [&](int kt, int buf) __attribute__((always_inline)) {
    const long pan = ((long)(ct * 16 + (kt >> 1))) * 8192;
    const int kk = kt & 1;
#pragma unroll
    for (int i = 0; i < 2; i++) {
      int gb = w * 2 + i;  // 8 groups, 4 waves x 2
      const short* src = WoG + pan + (gb * 2 + kk) * 512 + l * 8;
      gload_lds16(src, lds + buf * 8192 + 4096 + gb * 512);
    }
  };
  const unsigned lds0 = lds_addr(lds);
  auto process = [&](int buf) __attribute__((always_inline)) {
    const unsigned lbase = lds0 + buf * 16384;
    const unsigned aswz = (quad * 16 + (lm ^ (quad * 2))) * 16;
    s16x8 af[4], bfr[4];
#pragma unroll
    for (int mi = 0; mi < 4; mi++)
      af[mi] = ds_read_b128a(lbase + (wm * 4 + mi) * 1024 + aswz);
#pragma unroll
    for (int ni = 0; ni < 4; ni++)
      bfr[ni] = ds_read_b128a(lbase + 8192 + (wn * 4 + ni) * 1024 + l * 16);
    WAIT_LGKM0();
    __builtin_amdgcn_s_setprio(1);
#pragma unroll
    for (int mi = 0; mi < 4; mi++)
#pragma unroll
      for (int ni = 0; ni < 4; ni++)
        acc[mi][ni] = mfma_bf16(af[mi], bfr[ni], acc[mi][ni]);
    __builtin_amdgcn_s_setprio(0);
  };

  loadA(0);
  stageB(0, 0);
  stageB(1, 1);
  writeA(0);        // implicit wait for A(0) regs (B0,B1 stay in flight)
  WAIT_VMCNT(2);    // B(0) landed (B(1) outstanding)
  WAIT_LGKM0();
  __builtin_amdgcn_s_barrier();

  for (int kt = 0; kt < 32; ++kt) {
    if (kt + 1 < 32) loadA(kt + 1);
    if (kt + 2 < 32) stageB(kt + 2, (kt + 2) % 3);
    SCHED0();
    process(kt % 3);
    if (kt + 1 < 32) writeA((kt + 1) % 3);
    WAIT_VMCNT(2);
    WAIT_LGKM0();
    __builtin_amdgcn_s_barrier();
  }

  const int rowbase = row0 + wm * 64;
  const int colbase = col0 + wn * 64;
  for (int mi = 0; mi < 4; mi++)
    for (int r = 0; r < 4; r++) {
      int gr = rowbase + mi * 16 + quad * 4 + r;
      for (int ni = 0; ni < 4; ni++) {
        int gc = colbase + ni * 16 + lm;
        Out[(long)gr * DM + gc] = acc[mi][ni][r] + bias[gc];
      }
    }
}

// ---------------------------------------------------------------------------
extern "C" void kernel_launch(void* const* d_in, const int* in_sizes, int n_in,
                              void* d_out, int out_size, void* d_ws, size_t ws_size,
                              hipStream_t stream) {
  (void)in_sizes; (void)n_in; (void)out_size; (void)ws_size;
  const float* queries = (const float*)d_in[0];
  const float* keys    = (const float*)d_in[1];
  const float* values  = (const float*)d_in[2];
  const float* Wq = (const float*)d_in[3];
  const float* Wk = (const float*)d_in[4];
  const float* Wv = (const float*)d_in[5];
  const float* Wo = (const float*)d_in[6];
  const float* bo = (const float*)d_in[7];
  float* out = (float*)d_out;

  char* ws = (char*)d_ws;
  const size_t MB = 1024 * 1024;
  short* WqG = (short*)(ws + 0 * MB);   // 2 MiB each (group layout)
  short* WkG = (short*)(ws + 2 * MB);
  short* WvG = (short*)(ws + 4 * MB);
  short* WoG = (short*)(ws + 6 * MB);
  short* Qh  = (short*)(ws + 8 * MB);   // [B,H,2048,64] bf16 = 16 MiB
  short* KVg = (short*)(ws + 24 * MB);  // [bh][16 tiles][32 groups][64][8] = 32 MiB
  short* Obf = (short*)(ws + 56 * MB);  // [8192,1024] bf16 = 16 MiB (total 72)

  make_wgroups<<<dim3(16, 16, 4), 256, 0, stream>>>(
      Wq, Wk, Wv, Wo, WqG, WkG, WvG, WoG);
  proj_kernel<<<dim3(64, 4, 3), 512, 0, stream>>>(
      queries, keys, values, WqG, WkG, WvG, Qh, KVg);
  attn_kernel<<<dim3(64, 8), 512, 0, stream>>>(Qh, KVg, Obf);
  out_kernel<<<dim3(64, 8), 256, 0, stream>>>(Obf, WoG, bo, out);
}